// Round 10
// baseline (165.986 us; speedup 1.0000x reference)
//
#include <hip/hip_runtime.h>
#include <hip/hip_cooperative_groups.h>
#include <math.h>

#define N 2304
#define D 256
#define NH 8
#define HD 32
#define KS 6            // key segments in attention
#define SEG (N / KS)    // 384
#define NCH (SEG / 32)  // 12
#define NGR 2320        // guarded key count (2304 + 8 each side)
#define NBLK 432        // needs only 2 blocks/CU co-resident (cap 512)
#define NTHR 256

typedef __attribute__((ext_vector_type(8))) short short8;   // 8 bf16
typedef __attribute__((ext_vector_type(4))) short bf16x4;   // 4 bf16
typedef __attribute__((ext_vector_type(4))) float floatx4;  // 4 fp32 (MFMA C/D)

static __device__ __forceinline__ unsigned short f2bf(float x) {
  union { float f; unsigned u; } v; v.f = x;
  unsigned r = (v.u + 0x7fffu + ((v.u >> 16) & 1u)) >> 16;   // RNE
  return (unsigned short)r;
}
static __device__ __forceinline__ float bf2f(unsigned short h) {
  union { unsigned u; float f; } v; v.u = (unsigned)h << 16;
  return v.f;
}
static __device__ __forceinline__ unsigned pack2bf(float lo, float hi) {
  return (unsigned)f2bf(lo) | ((unsigned)f2bf(hi) << 16);
}

struct Params {
  const float *x1, *x2, *lng, *lnb, *ipw, *ipb, *ow, *ob;
  float *out;
  float *pacc, *psum;
  unsigned short *Qb, *Kb, *Vtb;
  unsigned short *x2b_full, *x2t_full;
  unsigned short *x1h, *x1l, *wh, *wl, *owh, *owl, *x2fh, *x2fl;
};

// ================= Phase 0: hi/lo splits + x2 bf16 prep ======================
static __device__ __forceinline__ void phase0_impl(const Params& P, char* smem)
{
  const int bid = blockIdx.x;
  const int t   = threadIdx.x;
  const int NB  = gridDim.x;
  for (int i = bid * NTHR + t; i < 851968; i += NB * NTHR) {
    const float* src; unsigned short *dh, *dl; int off;
    if (i < 589824)      { src = P.x1;  dh = P.x1h; dl = P.x1l; off = i; }
    else if (i < 786432) { src = P.ipw; dh = P.wh;  dl = P.wl;  off = i - 589824; }
    else                 { src = P.ow;  dh = P.owh; dl = P.owl; off = i - 786432; }
    const float v = src[off];
    const unsigned short h = f2bf(v);
    dh[off] = h;
    dl[off] = f2bf(v - bf2f(h));
  }
  unsigned short* T = (unsigned short*)smem;   // [16][17]
  const int tx = t & 15, ty = t >> 4;
  for (int u = bid; u < 145 * 16; u += NB) {
    const int k0 = (u % 145) * 16, f0 = (u / 145) * 16;
    const int key = k0 + ty - 8;
    unsigned short v = 0;
    if (key >= 0 && key < N) v = f2bf(P.x2[(size_t)key * D + f0 + tx]);
    P.x2b_full[(size_t)(k0 + ty) * D + f0 + tx] = v;
    T[ty * 17 + tx] = v;
    __syncthreads();
    P.x2t_full[(size_t)(f0 + ty) * NGR + k0 + tx] = T[tx * 17 + ty];
    __syncthreads();
  }
}

// ============== Phase 1: stage1 (bid<144) || KV-GEMM (144<=bid<288) ==========
static __device__ __forceinline__ void phase1_impl(const Params& P, char* smem)
{
  const int bid  = blockIdx.x;
  const int t    = threadIdx.x;
  const int wv   = t >> 6;
  const int lane = t & 63;
  const int g    = lane >> 4;
  const int c    = lane & 15;
  const unsigned short* x2b = P.x2b_full + 8 * D;
  const unsigned short* x2t = P.x2t_full + 8;

  if (bid < 144) {
    unsigned short* Pb = (unsigned short*)smem;       // [16][552]
    float* dn  = (float*)(smem + 17664);              // [4][16]
    float* lr1 = dn + 64;
    float* lr2 = lr1 + 64;
    const int r  = bid / 3;
    const int c0 = (bid % 3) * 16;
    const int qbase  = r * 48 + c0;
    const int row_lo = max(0, 8 - r);
    const int row_hi = min(16, 55 - r);
    const int nrows  = min(r + 8, 47) - max(r - 8, 0) + 1;

    short8 qf[8];
    {
      const unsigned short* qptr = x2b + (size_t)(qbase + c) * D + g * 8;
      #pragma unroll
      for (int si = 0; si < 8; ++si) qf[si] = *(const short8*)(qptr + si * 32);
    }

    float pssum[4] = {0.f, 0.f, 0.f, 0.f};
    for (int wr = row_lo + wv; wr <= row_hi; wr += 4) {
      const int kr = r - 8 + wr;
      const int keybase = kr * 48 + c0 - 8;
      #pragma unroll
      for (int ch = 0; ch < 2; ++ch) {
        const unsigned short* kptr = x2b + (size_t)(keybase + ch * 16 + c) * D + g * 8;
        floatx4 sa = {0.f, 0.f, 0.f, 0.f};
        #pragma unroll
        for (int si = 0; si < 8; ++si) {
          const short8 kf = *(const short8*)(kptr + si * 32);
          sa = __builtin_amdgcn_mfma_f32_16x16x32_bf16(qf[si], kf, sa, 0, 0, 0);
        }
        const int wc = ch * 16 + c;
        const int kc_img = c0 - 8 + wc;
        #pragma unroll
        for (int reg = 0; reg < 4; ++reg) {
          const int qi = g * 4 + reg;
          float sv = sa[reg] * 0.0625f;
          const int cimg  = c0 + qi;
          const int ncols = min(cimg + 8, 47) - max(cimg - 8, 0) + 1;
          const int mult  = 289 - nrows * ncols + 1;
          const int wc0q  = (cimg >= 8) ? qi : (8 - c0);
          if (mult > 1 && wr == row_lo && wc == wc0q) sv += __logf((float)mult);
          const bool valid = (kc_img >= 0) & (kc_img < 48) &
                             (wc >= qi) & (wc <= qi + 16);
          const float pv = valid ? __expf(sv) : 0.f;
          pssum[reg] += pv;
          Pb[qi * 552 + wr * 32 + wc] = valid ? f2bf(pv) : (unsigned short)0;
        }
      }
    }
    #pragma unroll
    for (int off = 1; off <= 8; off <<= 1) {
      #pragma unroll
      for (int reg = 0; reg < 4; ++reg) pssum[reg] += __shfl_xor(pssum[reg], off);
    }
    if (c == 0) {
      #pragma unroll
      for (int reg = 0; reg < 4; ++reg) dn[wv * 16 + g * 4 + reg] = pssum[reg];
    }
    __syncthreads();

    floatx4 acc[4];
    #pragma unroll
    for (int ng = 0; ng < 4; ++ng) acc[ng] = (floatx4){0.f, 0.f, 0.f, 0.f};
    const int fb = wv * 64;
    for (int wr = row_lo; wr <= row_hi; ++wr) {
      const int keybase = (r - 8 + wr) * 48 + c0 - 8;
      const short8 pA = *(const short8*)&Pb[c * 552 + wr * 32 + g * 8];
      #pragma unroll
      for (int ng = 0; ng < 4; ++ng) {
        const short8 vf = *(const short8*)(x2t + (size_t)(fb + ng * 16 + c) * NGR + keybase + g * 8);
        acc[ng] = __builtin_amdgcn_mfma_f32_16x16x32_bf16(pA, vf, acc[ng], 0, 0, 0);
      }
    }

    float vout[4][4], ps1[4] = {0,0,0,0}, ps2[4] = {0,0,0,0};
    #pragma unroll
    for (int reg = 0; reg < 4; ++reg) {
      const int m = g * 4 + reg;
      const float di = 1.f / (dn[m] + dn[16 + m] + dn[32 + m] + dn[48 + m]);
      #pragma unroll
      for (int ng = 0; ng < 4; ++ng) {
        const float v = acc[ng][reg] * di;
        vout[ng][reg] = v;
        ps1[reg] += v;
        ps2[reg] += v * v;
      }
    }
    #pragma unroll
    for (int off = 1; off <= 8; off <<= 1) {
      #pragma unroll
      for (int reg = 0; reg < 4; ++reg) {
        ps1[reg] += __shfl_xor(ps1[reg], off);
        ps2[reg] += __shfl_xor(ps2[reg], off);
      }
    }
    if (c == 0) {
      #pragma unroll
      for (int reg = 0; reg < 4; ++reg) {
        lr1[wv * 16 + g * 4 + reg] = ps1[reg];
        lr2[wv * 16 + g * 4 + reg] = ps2[reg];
      }
    }
    __syncthreads();
    #pragma unroll
    for (int reg = 0; reg < 4; ++reg) {
      const int m = g * 4 + reg;
      const float s1 = lr1[m] + lr1[16 + m] + lr1[32 + m] + lr1[48 + m];
      const float s2 = lr2[m] + lr2[16 + m] + lr2[32 + m] + lr2[48 + m];
      const float mu  = s1 * (1.f / 256.f);
      const float var = s2 * (1.f / 256.f) - mu * mu;
      const float rs  = rsqrtf(var + 1e-5f);
      #pragma unroll
      for (int ng = 0; ng < 4; ++ng) {
        const int f = fb + ng * 16 + c;
        const float val = (vout[ng][reg] - mu) * rs * P.lng[f] + P.lnb[f];
        const unsigned short h = f2bf(val);
        const size_t idx = (size_t)(qbase + m) * D + f;
        P.x2fh[idx] = h;
        P.x2fl[idx] = f2bf(val - bf2f(h));
      }
    }
  } else if (bid < 288) {
    const int idx = bid - 144;
    const int m0  = (idx >> 2) * 64;
    const int nw  = 256 + (idx & 3) * 128 + wv * 32;
    floatx4 acc[4][2];
    #pragma unroll
    for (int mt = 0; mt < 4; ++mt)
      #pragma unroll
      for (int nt = 0; nt < 2; ++nt) acc[mt][nt] = (floatx4){0.f, 0.f, 0.f, 0.f};
    #pragma unroll
    for (int pass = 0; pass < 3; ++pass) {
      const unsigned short* Ap = (pass == 1) ? P.x1l : P.x1h;
      const unsigned short* Wp = (pass == 2) ? P.wl : P.wh;
      for (int kc = 0; kc < 256; kc += 32) {
        short8 af[4], bf[2];
        #pragma unroll
        for (int mt = 0; mt < 4; ++mt)
          af[mt] = *(const short8*)(Ap + (size_t)(m0 + mt * 16 + c) * 256 + kc + g * 8);
        #pragma unroll
        for (int nt = 0; nt < 2; ++nt)
          bf[nt] = *(const short8*)(Wp + (size_t)(nw + nt * 16 + c) * 256 + kc + g * 8);
        #pragma unroll
        for (int mt = 0; mt < 4; ++mt)
          #pragma unroll
          for (int nt = 0; nt < 2; ++nt)
            acc[mt][nt] = __builtin_amdgcn_mfma_f32_16x16x32_bf16(af[mt], bf[nt], acc[mt][nt], 0, 0, 0);
      }
    }
    #pragma unroll
    for (int mt = 0; mt < 4; ++mt)
      #pragma unroll
      for (int nt = 0; nt < 2; ++nt) {
        const int j = nw + nt * 16 + c;
        const float bj = P.ipb[j];
        #pragma unroll
        for (int rr = 0; rr < 4; ++rr) {
          const int m = m0 + mt * 16 + 4 * g + rr;
          const float v = acc[mt][nt][rr] + bj;
          if (j < 512) P.Kb[(size_t)m * 256 + (j - 256)] = f2bf(v);
          else         P.Vtb[(size_t)(j - 512) * N + m] = f2bf(v);
        }
      }
  }
}

// ================= Phase 2: Q-GEMM (bid<72) ==================================
static __device__ __forceinline__ void phase2_impl(const Params& P)
{
  const int bid  = blockIdx.x;
  if (bid >= 72) return;
  const int t    = threadIdx.x;
  const int wv   = t >> 6;
  const int lane = t & 63;
  const int g    = lane >> 4;
  const int c    = lane & 15;
  const int m0 = (bid >> 1) * 64;
  const int nw = (bid & 1) * 128 + wv * 32;
  floatx4 acc[4][2];
  #pragma unroll
  for (int mt = 0; mt < 4; ++mt)
    #pragma unroll
    for (int nt = 0; nt < 2; ++nt) acc[mt][nt] = (floatx4){0.f, 0.f, 0.f, 0.f};
  #pragma unroll
  for (int pass = 0; pass < 3; ++pass) {
    const unsigned short* Ap = (pass == 1) ? P.x2fl : P.x2fh;
    const unsigned short* Wp = (pass == 2) ? P.wl : P.wh;   // rows 0..255 = Wq
    for (int kc = 0; kc < 256; kc += 32) {
      short8 af[4], bf[2];
      #pragma unroll
      for (int mt = 0; mt < 4; ++mt)
        af[mt] = *(const short8*)(Ap + (size_t)(m0 + mt * 16 + c) * 256 + kc + g * 8);
      #pragma unroll
      for (int nt = 0; nt < 2; ++nt)
        bf[nt] = *(const short8*)(Wp + (size_t)(nw + nt * 16 + c) * 256 + kc + g * 8);
      #pragma unroll
      for (int mt = 0; mt < 4; ++mt)
        #pragma unroll
        for (int nt = 0; nt < 2; ++nt)
          acc[mt][nt] = __builtin_amdgcn_mfma_f32_16x16x32_bf16(af[mt], bf[nt], acc[mt][nt], 0, 0, 0);
    }
  }
  const float qscale = 0.17677669529663687f;   // 1/sqrt(32)
  #pragma unroll
  for (int mt = 0; mt < 4; ++mt)
    #pragma unroll
    for (int nt = 0; nt < 2; ++nt) {
      const int j = nw + nt * 16 + c;
      const float bj = P.ipb[j];
      #pragma unroll
      for (int rr = 0; rr < 4; ++rr) {
        const int m = m0 + mt * 16 + 4 * g + rr;
        P.Qb[(size_t)m * 256 + j] = f2bf((acc[mt][nt][rr] + bj) * qscale);
      }
    }
}

// ================= Phase 3: flash attention (bid<432) ========================
static __device__ __forceinline__ void phase3_impl(const Params& P, char* smem)
{
  const int bid  = blockIdx.x;
  if (bid >= 432) return;
  const int t    = threadIdx.x;
  const int wv   = t >> 6;
  const int lane = t & 63;
  const int g    = lane >> 4;
  const int c    = lane & 15;
  unsigned short* Ksh = (unsigned short*)smem;   // [2][32*40]
  unsigned short* Vsh = Ksh + 2560;
  const int seg  = bid / 72;          // 0..5
  const int rest = bid % 72;
  const int qb   = rest >> 3;         // 0..8
  const int head = rest & 7;
  const int q0w  = qb * 256 + wv * 64;
  const int key0 = seg * SEG;

  short8 qf[4];
  #pragma unroll
  for (int qt = 0; qt < 4; ++qt)
    qf[qt] = *(const short8*)(P.Qb + (size_t)(q0w + qt * 16 + c) * D + head * HD + g * 8);

  const int tt = t & 127;
  const bool isK = (t < 128);
  const unsigned short* src = isK
      ? P.Kb  + (size_t)(key0 + tt / 4) * D + head * HD + (tt % 4) * 8
      : P.Vtb + (size_t)(head * HD + tt / 4) * N + key0 + (tt % 4) * 8;
  const size_t sstep = isK ? (size_t)32 * D : (size_t)32;
  unsigned short* dstbase = (isK ? Ksh : Vsh) + (tt / 4) * 40 + (tt % 4) * 8;

  *(float4*)dstbase = *(const float4*)src;
  __syncthreads();

  floatx4 accL[4], accH[4];
  float ssum[4];
  #pragma unroll
  for (int qt = 0; qt < 4; ++qt) {
    accL[qt] = (floatx4){0.f, 0.f, 0.f, 0.f};
    accH[qt] = (floatx4){0.f, 0.f, 0.f, 0.f};
    ssum[qt] = 0.f;
  }

  for (int ch = 0; ch < NCH; ++ch) {
    float4 gpre;
    const bool more = (ch + 1 < NCH);
    if (more) gpre = *(const float4*)(src + sstep * (ch + 1));
    const unsigned short* kb = Ksh + (ch & 1) * 1280;
    const unsigned short* vb = Vsh + (ch & 1) * 1280;
    #pragma unroll
    for (int kk = 0; kk < 2; ++kk) {
      const short8 kf  = *(const short8*)&kb[(kk * 16 + c) * 40 + g * 8];
      const bf16x4 vf0 = *(const bf16x4*)&vb[c * 40 + kk * 16 + g * 4];
      const bf16x4 vf1 = *(const bf16x4*)&vb[(16 + c) * 40 + kk * 16 + g * 4];
      #pragma unroll
      for (int qt = 0; qt < 4; ++qt) {
        const floatx4 z = {0.f, 0.f, 0.f, 0.f};
        floatx4 sA = __builtin_amdgcn_mfma_f32_16x16x32_bf16(kf, qf[qt], z, 0, 0, 0);
        const float p0 = __expf(sA[0]);
        const float p1 = __expf(sA[1]);
        const float p2 = __expf(sA[2]);
        const float p3 = __expf(sA[3]);
        ssum[qt] += (p0 + p1) + (p2 + p3);
        union { unsigned u[2]; bf16x4 s; } pB;
        pB.u[0] = pack2bf(p0, p1);
        pB.u[1] = pack2bf(p2, p3);
        accL[qt] = __builtin_amdgcn_mfma_f32_16x16x16bf16_1k(vf0, pB.s, accL[qt], 0, 0, 0);
        accH[qt] = __builtin_amdgcn_mfma_f32_16x16x16bf16_1k(vf1, pB.s, accH[qt], 0, 0, 0);
      }
    }
    if (more) *(float4*)(dstbase + ((ch + 1) & 1) * 1280) = gpre;
    __syncthreads();
  }

  #pragma unroll
  for (int qt = 0; qt < 4; ++qt) {
    float s = ssum[qt];
    s += __shfl_xor(s, 16);
    s += __shfl_xor(s, 32);
    const size_t row = (size_t)(seg * NH + head) * N + q0w + qt * 16 + c;
    *(float4*)(P.pacc + row * HD + g * 4) =
        make_float4(accL[qt][0], accL[qt][1], accL[qt][2], accL[qt][3]);
    *(float4*)(P.pacc + row * HD + 16 + g * 4) =
        make_float4(accH[qt][0], accH[qt][1], accH[qt][2], accH[qt][3]);
    if (g == 0) P.psum[row] = s;
  }
}

// ================= Phase 4: combine + out-projection (bid<72) ================
static __device__ __forceinline__ void phase4_impl(const Params& P, char* smem)
{
  const int bid  = blockIdx.x;
  if (bid >= 72) return;
  const int t    = threadIdx.x;
  const int wv   = t >> 6;
  const int lane = t & 63;
  const int g    = lane >> 4;
  const int c    = lane & 15;
  unsigned short* oht = (unsigned short*)smem;    // [32][264]
  unsigned short* olt = oht + 32 * 264;
  const int m0 = bid * 32;
  {
    const int row = t >> 3;
    const int hh  = t & 7;
    const int mrow = m0 + row;
    float den = 0.f;
    #pragma unroll
    for (int sgi = 0; sgi < KS; ++sgi)
      den += P.psum[(size_t)(sgi * NH + hh) * N + mrow];
    const float dinv = 1.f / den;
    #pragma unroll
    for (int c4 = 0; c4 < 8; ++c4) {
      float ax = 0.f, ay = 0.f, az = 0.f, aw = 0.f;
      #pragma unroll
      for (int sgi = 0; sgi < KS; ++sgi) {
        const float4 pv = *(const float4*)&P.pacc[((size_t)(sgi * NH + hh) * N + mrow) * HD + c4 * 4];
        ax += pv.x; ay += pv.y; az += pv.z; aw += pv.w;
      }
      const int f0 = hh * 32 + c4 * 4;
      const float vv[4] = {ax * dinv, ay * dinv, az * dinv, aw * dinv};
      #pragma unroll
      for (int e = 0; e < 4; ++e) {
        const unsigned short h = f2bf(vv[e]);
        oht[row * 264 + f0 + e] = h;
        olt[row * 264 + f0 + e] = f2bf(vv[e] - bf2f(h));
      }
    }
  }
  __syncthreads();

  const int nw = wv * 64;
  floatx4 acc[2][4];
  #pragma unroll
  for (int mt = 0; mt < 2; ++mt)
    #pragma unroll
    for (int nt = 0; nt < 4; ++nt) acc[mt][nt] = (floatx4){0.f, 0.f, 0.f, 0.f};
  #pragma unroll
  for (int pass = 0; pass < 3; ++pass) {
    const unsigned short* Ap = (pass == 1) ? olt : oht;
    const unsigned short* Wp = (pass == 2) ? P.owl : P.owh;
    #pragma unroll
    for (int kc = 0; kc < 256; kc += 32) {
      short8 af[2], bf[4];
      #pragma unroll
      for (int mt = 0; mt < 2; ++mt)
        af[mt] = *(const short8*)&Ap[(mt * 16 + c) * 264 + kc + g * 8];
      #pragma unroll
      for (int nt = 0; nt < 4; ++nt)
        bf[nt] = *(const short8*)(Wp + (size_t)(nw + nt * 16 + c) * 256 + kc + g * 8);
      #pragma unroll
      for (int mt = 0; mt < 2; ++mt)
        #pragma unroll
        for (int nt = 0; nt < 4; ++nt)
          acc[mt][nt] = __builtin_amdgcn_mfma_f32_16x16x32_bf16(af[mt], bf[nt], acc[mt][nt], 0, 0, 0);
    }
  }
  #pragma unroll
  for (int mt = 0; mt < 2; ++mt)
    #pragma unroll
    for (int nt = 0; nt < 4; ++nt) {
      const int j = nw + nt * 16 + c;
      const float bj = P.ob[j];
      #pragma unroll
      for (int rr = 0; rr < 4; ++rr) {
        const int m = m0 + mt * 16 + 4 * g + rr;
        P.out[(size_t)m * 256 + j] = acc[mt][nt][rr] + bj;
      }
    }
}

// ================= Mega (cooperative) and fallback wrappers ==================
__global__ __launch_bounds__(NTHR, 2) void mega_kernel(Params P)
{
  __shared__ __align__(16) char smem[33792];
  cooperative_groups::grid_group grid = cooperative_groups::this_grid();
  phase0_impl(P, smem);
  grid.sync();
  phase1_impl(P, smem);
  grid.sync();
  phase2_impl(P);
  grid.sync();
  phase3_impl(P, smem);
  grid.sync();
  phase4_impl(P, smem);
}

__global__ __launch_bounds__(NTHR) void phase0_kernel(Params P)
{ __shared__ __align__(16) char smem[33792]; phase0_impl(P, smem); }
__global__ __launch_bounds__(NTHR) void phase1_kernel(Params P)
{ __shared__ __align__(16) char smem[33792]; phase1_impl(P, smem); }
__global__ __launch_bounds__(NTHR) void phase2_kernel(Params P)
{ phase2_impl(P); }
__global__ __launch_bounds__(NTHR) void phase3_kernel(Params P)
{ __shared__ __align__(16) char smem[33792]; phase3_impl(P, smem); }
__global__ __launch_bounds__(NTHR) void phase4_kernel(Params P)
{ __shared__ __align__(16) char smem[33792]; phase4_impl(P, smem); }

extern "C" void kernel_launch(void* const* d_in, const int* in_sizes, int n_in,
                              void* d_out, int out_size, void* d_ws, size_t ws_size,
                              hipStream_t stream)
{
  (void)in_sizes; (void)n_in; (void)out_size; (void)ws_size;
  Params P;
  P.x1  = (const float*)d_in[0];
  P.x2  = (const float*)d_in[1];
  P.lng = (const float*)d_in[2];
  P.lnb = (const float*)d_in[3];
  P.ipw = (const float*)d_in[4];
  P.ipb = (const float*)d_in[5];
  P.ow  = (const float*)d_in[6];
  P.ob  = (const float*)d_in[7];
  P.out = (float*)d_out;

  char* p = (char*)d_ws;
  P.pacc = (float*)p;          p += (size_t)KS * NH * N * HD * 4;
  P.psum = (float*)p;          p += (size_t)KS * NH * N * 4;
  P.Qb   = (unsigned short*)p; p += (size_t)N * D * 2;
  P.Kb   = (unsigned short*)p; p += (size_t)N * D * 2;
  P.Vtb  = (unsigned short*)p; p += (size_t)D * N * 2;
  P.x2b_full = (unsigned short*)p; p += (size_t)NGR * D * 2;
  P.x2t_full = (unsigned short*)p; p += (size_t)D * NGR * 2;
  P.x1h  = (unsigned short*)p; p += (size_t)N * D * 2;
  P.x1l  = (unsigned short*)p; p += (size_t)N * D * 2;
  P.wh   = (unsigned short*)p; p += (size_t)768 * 256 * 2;
  P.wl   = (unsigned short*)p; p += (size_t)768 * 256 * 2;
  P.owh  = (unsigned short*)p; p += (size_t)256 * 256 * 2;
  P.owl  = (unsigned short*)p; p += (size_t)256 * 256 * 2;
  P.x2fh = (unsigned short*)p; p += (size_t)N * D * 2;
  P.x2fl = (unsigned short*)p; p += (size_t)N * D * 2;

  // Host-side (capture-safe, deterministic) capacity check for cooperative fit.
  int nb = 0, cus = 0;
  hipError_t oe = hipOccupancyMaxActiveBlocksPerMultiprocessor(
      &nb, (const void*)mega_kernel, NTHR, 0);
  hipDeviceGetAttribute(&cus, hipDeviceAttributeMultiprocessorCount, 0);
  bool coop = (oe == hipSuccess) && ((long)nb * (long)cus >= (long)NBLK);

  hipError_t err = hipErrorUnknown;
  if (coop) {
    void* args[] = { &P };
    err = hipLaunchCooperativeKernel((void*)mega_kernel, dim3(NBLK), dim3(NTHR),
                                     args, 0, stream);
  }
  if (!coop || err != hipSuccess) {
    phase0_kernel<<<NBLK, NTHR, 0, stream>>>(P);
    phase1_kernel<<<288, NTHR, 0, stream>>>(P);
    phase2_kernel<<<72, NTHR, 0, stream>>>(P);
    phase3_kernel<<<NBLK, NTHR, 0, stream>>>(P);
    phase4_kernel<<<72, NTHR, 0, stream>>>(P);
  }
}

// Round 11
// 159.698 us; speedup vs baseline: 1.0394x; 1.0394x over previous
//
#include <hip/hip_runtime.h>
#include <math.h>

#define N 2304
#define D 256
#define NH 8
#define HD 32
#define KS 8            // key segments in attention
#define SEG (N / KS)    // 288
#define NCH (SEG / 32)  // 9
#define NGR 2320        // guarded key count (2304 + 8 each side)

typedef __attribute__((ext_vector_type(8))) short short8;   // 8 bf16
typedef __attribute__((ext_vector_type(4))) short bf16x4;   // 4 bf16
typedef __attribute__((ext_vector_type(4))) float floatx4;  // 4 fp32 (MFMA C/D)

static __device__ __forceinline__ unsigned short f2bf(float x) {
  union { float f; unsigned u; } v; v.f = x;
  unsigned r = (v.u + 0x7fffu + ((v.u >> 16) & 1u)) >> 16;   // RNE
  return (unsigned short)r;
}
static __device__ __forceinline__ float bf2f(unsigned short h) {
  union { unsigned u; float f; } v; v.u = (unsigned)h << 16;
  return v.f;
}
static __device__ __forceinline__ unsigned pack2bf(float lo, float hi) {
  return (unsigned)f2bf(lo) | ((unsigned)f2bf(hi) << 16);
}

struct Params {
  const float *x1, *x2, *lng, *lnb, *ipw, *ipb, *ow, *ob;
  float *out;
  float *pacc, *psum;
  unsigned short *Qb, *Kb, *Vtb;
  unsigned short *x2b_full, *x2t_full;
  unsigned short *wh, *wl, *owh, *owl;
};

// ============ K1: W hi/lo split + x2 bf16 row-major/transposed prep ==========
__global__ __launch_bounds__(256) void prep_kernel(Params P)
{
  __shared__ unsigned short T[16][17];
  const int t = threadIdx.x, bid = blockIdx.x, NB = gridDim.x;
  for (int i = bid * 256 + t; i < 262144; i += NB * 256) {
    const float* src; unsigned short *dh, *dl; int off;
    if (i < 196608) { src = P.ipw; dh = P.wh;  dl = P.wl;  off = i; }
    else            { src = P.ow;  dh = P.owh; dl = P.owl; off = i - 196608; }
    const float v = src[off];
    const unsigned short h = f2bf(v);
    dh[off] = h;
    dl[off] = f2bf(v - bf2f(h));
  }
  const int tx = t & 15, ty = t >> 4;
  for (int u = bid; u < 145 * 16; u += NB) {
    const int k0 = (u % 145) * 16, f0 = (u / 145) * 16;
    const int key = k0 + ty - 8;
    unsigned short v = 0;
    if (key >= 0 && key < N) v = f2bf(P.x2[(size_t)key * D + f0 + tx]);
    P.x2b_full[(size_t)(k0 + ty) * D + f0 + tx] = v;
    T[ty][tx] = v;
    __syncthreads();
    P.x2t_full[(size_t)(f0 + ty) * NGR + k0 + tx] = T[tx][ty];
    __syncthreads();
  }
}

// ===== K2: blocks 0..143 stage1+Q-proj (x2f stays in LDS); 144..287 KV-GEMM ==
__global__ __launch_bounds__(256) void mid_kernel(Params P)
{
  __shared__ __align__(16) unsigned short Pb[16 * 552];   // probs, bf16
  __shared__ __align__(16) unsigned short xfh[16 * 264];  // x2f hi (stride 264)
  __shared__ __align__(16) unsigned short xfl[16 * 264];  // x2f lo
  __shared__ float dn[64], lr1[64], lr2[64];

  const int bid  = blockIdx.x;
  const int t    = threadIdx.x;
  const int wv   = t >> 6;
  const int lane = t & 63;
  const int g    = lane >> 4;
  const int c    = lane & 15;
  const unsigned short* x2b = P.x2b_full + 8 * D;
  const unsigned short* x2t = P.x2t_full + 8;

  if (bid < 144) {
    // ---- stage1: MFMA window attention + LN (inline masked exp) ----
    const int r  = bid / 3;
    const int c0 = (bid % 3) * 16;
    const int qbase  = r * 48 + c0;
    const int row_lo = max(0, 8 - r);
    const int row_hi = min(16, 55 - r);
    const int nrows  = min(r + 8, 47) - max(r - 8, 0) + 1;

    short8 qf[8];
    {
      const unsigned short* qptr = x2b + (size_t)(qbase + c) * D + g * 8;
      #pragma unroll
      for (int si = 0; si < 8; ++si) qf[si] = *(const short8*)(qptr + si * 32);
    }

    float pssum[4] = {0.f, 0.f, 0.f, 0.f};
    for (int wr = row_lo + wv; wr <= row_hi; wr += 4) {
      const int kr = r - 8 + wr;
      const int keybase = kr * 48 + c0 - 8;
      #pragma unroll
      for (int ch = 0; ch < 2; ++ch) {
        const unsigned short* kptr = x2b + (size_t)(keybase + ch * 16 + c) * D + g * 8;
        floatx4 sa = {0.f, 0.f, 0.f, 0.f};
        #pragma unroll
        for (int si = 0; si < 8; ++si) {
          const short8 kf = *(const short8*)(kptr + si * 32);
          sa = __builtin_amdgcn_mfma_f32_16x16x32_bf16(qf[si], kf, sa, 0, 0, 0);
        }
        const int wc = ch * 16 + c;
        const int kc_img = c0 - 8 + wc;
        #pragma unroll
        for (int reg = 0; reg < 4; ++reg) {
          const int qi = g * 4 + reg;
          float sv = sa[reg] * 0.0625f;
          const int cimg  = c0 + qi;
          const int ncols = min(cimg + 8, 47) - max(cimg - 8, 0) + 1;
          const int mult  = 289 - nrows * ncols + 1;
          const int wc0q  = (cimg >= 8) ? qi : (8 - c0);
          if (mult > 1 && wr == row_lo && wc == wc0q) sv += __logf((float)mult);
          const bool valid = (kc_img >= 0) & (kc_img < 48) &
                             (wc >= qi) & (wc <= qi + 16);
          const float pv = valid ? __expf(sv) : 0.f;
          pssum[reg] += pv;
          Pb[qi * 552 + wr * 32 + wc] = valid ? f2bf(pv) : (unsigned short)0;
        }
      }
    }
    #pragma unroll
    for (int off = 1; off <= 8; off <<= 1) {
      #pragma unroll
      for (int reg = 0; reg < 4; ++reg) pssum[reg] += __shfl_xor(pssum[reg], off);
    }
    if (c == 0) {
      #pragma unroll
      for (int reg = 0; reg < 4; ++reg) dn[wv * 16 + g * 4 + reg] = pssum[reg];
    }
    __syncthreads();

    floatx4 acc[4];
    #pragma unroll
    for (int ng = 0; ng < 4; ++ng) acc[ng] = (floatx4){0.f, 0.f, 0.f, 0.f};
    const int fb = wv * 64;
    for (int wr = row_lo; wr <= row_hi; ++wr) {
      const int keybase = (r - 8 + wr) * 48 + c0 - 8;
      const short8 pA = *(const short8*)&Pb[c * 552 + wr * 32 + g * 8];
      #pragma unroll
      for (int ng = 0; ng < 4; ++ng) {
        const short8 vf = *(const short8*)(x2t + (size_t)(fb + ng * 16 + c) * NGR + keybase + g * 8);
        acc[ng] = __builtin_amdgcn_mfma_f32_16x16x32_bf16(pA, vf, acc[ng], 0, 0, 0);
      }
    }

    float vout[4][4], ps1[4] = {0,0,0,0}, ps2[4] = {0,0,0,0};
    #pragma unroll
    for (int reg = 0; reg < 4; ++reg) {
      const int m = g * 4 + reg;
      const float di = 1.f / (dn[m] + dn[16 + m] + dn[32 + m] + dn[48 + m]);
      #pragma unroll
      for (int ng = 0; ng < 4; ++ng) {
        const float v = acc[ng][reg] * di;
        vout[ng][reg] = v;
        ps1[reg] += v;
        ps2[reg] += v * v;
      }
    }
    #pragma unroll
    for (int off = 1; off <= 8; off <<= 1) {
      #pragma unroll
      for (int reg = 0; reg < 4; ++reg) {
        ps1[reg] += __shfl_xor(ps1[reg], off);
        ps2[reg] += __shfl_xor(ps2[reg], off);
      }
    }
    if (c == 0) {
      #pragma unroll
      for (int reg = 0; reg < 4; ++reg) {
        lr1[wv * 16 + g * 4 + reg] = ps1[reg];
        lr2[wv * 16 + g * 4 + reg] = ps2[reg];
      }
    }
    __syncthreads();
    #pragma unroll
    for (int reg = 0; reg < 4; ++reg) {
      const int m = g * 4 + reg;
      const float s1 = lr1[m] + lr1[16 + m] + lr1[32 + m] + lr1[48 + m];
      const float s2 = lr2[m] + lr2[16 + m] + lr2[32 + m] + lr2[48 + m];
      const float mu  = s1 * (1.f / 256.f);
      const float var = s2 * (1.f / 256.f) - mu * mu;
      const float rs  = rsqrtf(var + 1e-5f);
      #pragma unroll
      for (int ng = 0; ng < 4; ++ng) {
        const int f = fb + ng * 16 + c;
        const float val = (vout[ng][reg] - mu) * rs * P.lng[f] + P.lnb[f];
        const unsigned short h = f2bf(val);
        xfh[m * 264 + f] = h;
        xfl[m * 264 + f] = f2bf(val - bf2f(h));
      }
    }
    __syncthreads();

    // ---- fused Q projection: 3-pass split-bf16 MFMA, A from LDS ----
    const int nw = wv * 64;
    floatx4 qacc[4];
    #pragma unroll
    for (int nt = 0; nt < 4; ++nt) qacc[nt] = (floatx4){0.f, 0.f, 0.f, 0.f};
    for (int kc = 0; kc < 256; kc += 32) {
      const short8 ah = *(const short8*)&xfh[c * 264 + kc + g * 8];
      const short8 al = *(const short8*)&xfl[c * 264 + kc + g * 8];
      #pragma unroll
      for (int nt = 0; nt < 4; ++nt) {
        const short8 bh = *(const short8*)(P.wh + (size_t)(nw + nt * 16 + c) * 256 + kc + g * 8);
        const short8 bl = *(const short8*)(P.wl + (size_t)(nw + nt * 16 + c) * 256 + kc + g * 8);
        qacc[nt] = __builtin_amdgcn_mfma_f32_16x16x32_bf16(ah, bh, qacc[nt], 0, 0, 0);
        qacc[nt] = __builtin_amdgcn_mfma_f32_16x16x32_bf16(al, bh, qacc[nt], 0, 0, 0);
        qacc[nt] = __builtin_amdgcn_mfma_f32_16x16x32_bf16(ah, bl, qacc[nt], 0, 0, 0);
      }
    }
    const float qscale = 0.17677669529663687f;   // 1/sqrt(32)
    #pragma unroll
    for (int nt = 0; nt < 4; ++nt) {
      const int j = nw + nt * 16 + c;
      const float bj = P.ipb[j];
      #pragma unroll
      for (int reg = 0; reg < 4; ++reg) {
        const int m = qbase + 4 * g + reg;
        P.Qb[(size_t)m * 256 + j] = f2bf((qacc[nt][reg] + bj) * qscale);
      }
    }
  } else if (bid < 288) {
    // ---- KV-GEMM: 3-pass split-bf16 MFMA, x1 converted inline ----
    const int idx = bid - 144;
    const int m0  = (idx >> 2) * 64;
    const int nw  = 256 + (idx & 3) * 128 + wv * 32;
    floatx4 acc[4][2];
    #pragma unroll
    for (int mt = 0; mt < 4; ++mt)
      #pragma unroll
      for (int nt = 0; nt < 2; ++nt) acc[mt][nt] = (floatx4){0.f, 0.f, 0.f, 0.f};

    for (int kc = 0; kc < 256; kc += 32) {
      short8 ah[4], al[4];
      #pragma unroll
      for (int mt = 0; mt < 4; ++mt) {
        const float* xp = P.x1 + (size_t)(m0 + mt * 16 + c) * 256 + kc + g * 8;
        const float4 va = *(const float4*)xp;
        const float4 vb = *(const float4*)(xp + 4);
        const float vv[8] = {va.x, va.y, va.z, va.w, vb.x, vb.y, vb.z, vb.w};
        #pragma unroll
        for (int e = 0; e < 8; ++e) {
          const unsigned short h = f2bf(vv[e]);
          ah[mt][e] = (short)h;
          al[mt][e] = (short)f2bf(vv[e] - bf2f(h));
        }
      }
      short8 bh[2], bl[2];
      #pragma unroll
      for (int nt = 0; nt < 2; ++nt) {
        bh[nt] = *(const short8*)(P.wh + (size_t)(nw + nt * 16 + c) * 256 + kc + g * 8);
        bl[nt] = *(const short8*)(P.wl + (size_t)(nw + nt * 16 + c) * 256 + kc + g * 8);
      }
      #pragma unroll
      for (int mt = 0; mt < 4; ++mt)
        #pragma unroll
        for (int nt = 0; nt < 2; ++nt) {
          acc[mt][nt] = __builtin_amdgcn_mfma_f32_16x16x32_bf16(ah[mt], bh[nt], acc[mt][nt], 0, 0, 0);
          acc[mt][nt] = __builtin_amdgcn_mfma_f32_16x16x32_bf16(al[mt], bh[nt], acc[mt][nt], 0, 0, 0);
          acc[mt][nt] = __builtin_amdgcn_mfma_f32_16x16x32_bf16(ah[mt], bl[nt], acc[mt][nt], 0, 0, 0);
        }
    }
    #pragma unroll
    for (int mt = 0; mt < 4; ++mt)
      #pragma unroll
      for (int nt = 0; nt < 2; ++nt) {
        const int j = nw + nt * 16 + c;
        const float bj = P.ipb[j];
        #pragma unroll
        for (int rr = 0; rr < 4; ++rr) {
          const int m = m0 + mt * 16 + 4 * g + rr;
          const float v = acc[mt][nt][rr] + bj;
          if (j < 512) P.Kb[(size_t)m * 256 + (j - 256)] = f2bf(v);
          else         P.Vtb[(size_t)(j - 512) * N + m] = f2bf(v);
        }
      }
  }
}

// ============ K3: MFMA flash attention (R8 config: KS=8, 128 thr) ============
__global__ __launch_bounds__(128) void attn_kernel(Params P)
{
  __shared__ __align__(16) unsigned short Ksh[2][32 * 40];
  __shared__ __align__(16) unsigned short Vsh[2][32 * 40];

  const int t    = threadIdx.x;
  const int wv   = t >> 6;
  const int lane = t & 63;
  const int g    = lane >> 4;
  const int c    = lane & 15;
  const int seg  = blockIdx.x;
  const int qb   = blockIdx.y;
  const int head = blockIdx.z;
  const int q0w  = qb * 128 + wv * 64;
  const int key0 = seg * SEG;

  short8 qf[4];
  #pragma unroll
  for (int qt = 0; qt < 4; ++qt)
    qf[qt] = *(const short8*)(P.Qb + (size_t)(q0w + qt * 16 + c) * D + head * HD + g * 8);

  const unsigned short* ksrc = P.Kb  + (size_t)(key0 + t / 4) * D + head * HD + (t % 4) * 8;
  const unsigned short* vsrc = P.Vtb + (size_t)(head * HD + t / 4) * N + key0 + (t % 4) * 8;
  const int sdst = (t / 4) * 40 + (t % 4) * 8;

  {
    const float4 gk = *(const float4*)ksrc;
    const float4 gv = *(const float4*)vsrc;
    *(float4*)&Ksh[0][sdst] = gk;
    *(float4*)&Vsh[0][sdst] = gv;
  }
  __syncthreads();

  floatx4 accL[4], accH[4];
  float ssum[4];
  #pragma unroll
  for (int qt = 0; qt < 4; ++qt) {
    accL[qt] = (floatx4){0.f, 0.f, 0.f, 0.f};
    accH[qt] = (floatx4){0.f, 0.f, 0.f, 0.f};
    ssum[qt] = 0.f;
  }

  for (int ch = 0; ch < NCH; ++ch) {
    float4 gk, gv;
    const bool more = (ch + 1 < NCH);
    if (more) {
      gk = *(const float4*)(ksrc + (size_t)(ch + 1) * 32 * D);
      gv = *(const float4*)(vsrc + (ch + 1) * 32);
    }
    const unsigned short* kb = Ksh[ch & 1];
    const unsigned short* vb = Vsh[ch & 1];

    #pragma unroll
    for (int kk = 0; kk < 2; ++kk) {
      const short8 kf  = *(const short8*)&kb[(kk * 16 + c) * 40 + g * 8];
      const bf16x4 vf0 = *(const bf16x4*)&vb[c * 40 + kk * 16 + g * 4];
      const bf16x4 vf1 = *(const bf16x4*)&vb[(16 + c) * 40 + kk * 16 + g * 4];
      #pragma unroll
      for (int qt = 0; qt < 4; ++qt) {
        const floatx4 z = {0.f, 0.f, 0.f, 0.f};
        floatx4 sA = __builtin_amdgcn_mfma_f32_16x16x32_bf16(kf, qf[qt], z, 0, 0, 0);
        const float p0 = __expf(sA[0]);
        const float p1 = __expf(sA[1]);
        const float p2 = __expf(sA[2]);
        const float p3 = __expf(sA[3]);
        ssum[qt] += (p0 + p1) + (p2 + p3);
        union { unsigned u[2]; bf16x4 s; } pB;
        pB.u[0] = pack2bf(p0, p1);
        pB.u[1] = pack2bf(p2, p3);
        accL[qt] = __builtin_amdgcn_mfma_f32_16x16x16bf16_1k(vf0, pB.s, accL[qt], 0, 0, 0);
        accH[qt] = __builtin_amdgcn_mfma_f32_16x16x16bf16_1k(vf1, pB.s, accH[qt], 0, 0, 0);
      }
    }
    if (more) {
      *(float4*)&Ksh[(ch + 1) & 1][sdst] = gk;
      *(float4*)&Vsh[(ch + 1) & 1][sdst] = gv;
    }
    __syncthreads();
  }

  #pragma unroll
  for (int qt = 0; qt < 4; ++qt) {
    float s = ssum[qt];
    s += __shfl_xor(s, 16);
    s += __shfl_xor(s, 32);
    const size_t row = (size_t)(seg * NH + head) * N + q0w + qt * 16 + c;
    *(float4*)(P.pacc + row * HD + g * 4) =
        make_float4(accL[qt][0], accL[qt][1], accL[qt][2], accL[qt][3]);
    *(float4*)(P.pacc + row * HD + 16 + g * 4) =
        make_float4(accH[qt][0], accH[qt][1], accH[qt][2], accH[qt][3]);
    if (g == 0) P.psum[row] = s;
  }
}

// ============ K4: combine + out-projection (fused, 72 blocks) ================
__global__ __launch_bounds__(256) void tail_kernel(Params P)
{
  __shared__ __align__(16) unsigned short oht[32 * 264];
  __shared__ __align__(16) unsigned short olt[32 * 264];
  const int bid  = blockIdx.x;
  const int t    = threadIdx.x;
  const int wv   = t >> 6;
  const int lane = t & 63;
  const int g    = lane >> 4;
  const int c    = lane & 15;
  const int m0 = bid * 32;
  {
    const int row = t >> 3;
    const int hh  = t & 7;
    const int mrow = m0 + row;
    float den = 0.f;
    #pragma unroll
    for (int sgi = 0; sgi < KS; ++sgi)
      den += P.psum[(size_t)(sgi * NH + hh) * N + mrow];
    const float dinv = 1.f / den;
    #pragma unroll
    for (int c4 = 0; c4 < 8; ++c4) {
      float ax = 0.f, ay = 0.f, az = 0.f, aw = 0.f;
      #pragma unroll
      for (int sgi = 0; sgi < KS; ++sgi) {
        const float4 pv = *(const float4*)&P.pacc[((size_t)(sgi * NH + hh) * N + mrow) * HD + c4 * 4];
        ax += pv.x; ay += pv.y; az += pv.z; aw += pv.w;
      }
      const int f0 = hh * 32 + c4 * 4;
      const float vv[4] = {ax * dinv, ay * dinv, az * dinv, aw * dinv};
      #pragma unroll
      for (int e = 0; e < 4; ++e) {
        const unsigned short h = f2bf(vv[e]);
        oht[row * 264 + f0 + e] = h;
        olt[row * 264 + f0 + e] = f2bf(vv[e] - bf2f(h));
      }
    }
  }
  __syncthreads();

  const int nw = wv * 64;
  floatx4 acc[2][4];
  #pragma unroll
  for (int mt = 0; mt < 2; ++mt)
    #pragma unroll
    for (int nt = 0; nt < 4; ++nt) acc[mt][nt] = (floatx4){0.f, 0.f, 0.f, 0.f};
  #pragma unroll
  for (int pass = 0; pass < 3; ++pass) {
    const unsigned short* Ap = (pass == 1) ? olt : oht;
    const unsigned short* Wp = (pass == 2) ? P.owl : P.owh;
    #pragma unroll
    for (int kc = 0; kc < 256; kc += 32) {
      short8 af[2], bf[4];
      #pragma unroll
      for (int mt = 0; mt < 2; ++mt)
        af[mt] = *(const short8*)&Ap[(mt * 16 + c) * 264 + kc + g * 8];
      #pragma unroll
      for (int nt = 0; nt < 4; ++nt)
        bf[nt] = *(const short8*)(Wp + (size_t)(nw + nt * 16 + c) * 256 + kc + g * 8);
      #pragma unroll
      for (int mt = 0; mt < 2; ++mt)
        #pragma unroll
        for (int nt = 0; nt < 4; ++nt)
          acc[mt][nt] = __builtin_amdgcn_mfma_f32_16x16x32_bf16(af[mt], bf[nt], acc[mt][nt], 0, 0, 0);
    }
  }
  #pragma unroll
  for (int mt = 0; mt < 2; ++mt)
    #pragma unroll
    for (int nt = 0; nt < 4; ++nt) {
      const int j = nw + nt * 16 + c;
      const float bj = P.ob[j];
      #pragma unroll
      for (int rr = 0; rr < 4; ++rr) {
        const int m = m0 + mt * 16 + 4 * g + rr;
        P.out[(size_t)m * 256 + j] = acc[mt][nt][rr] + bj;
      }
    }
}

extern "C" void kernel_launch(void* const* d_in, const int* in_sizes, int n_in,
                              void* d_out, int out_size, void* d_ws, size_t ws_size,
                              hipStream_t stream)
{
  (void)in_sizes; (void)n_in; (void)out_size; (void)ws_size;
  Params P;
  P.x1  = (const float*)d_in[0];
  P.x2  = (const float*)d_in[1];
  P.lng = (const float*)d_in[2];
  P.lnb = (const float*)d_in[3];
  P.ipw = (const float*)d_in[4];
  P.ipb = (const float*)d_in[5];
  P.ow  = (const float*)d_in[6];
  P.ob  = (const float*)d_in[7];
  P.out = (float*)d_out;

  char* p = (char*)d_ws;
  P.pacc = (float*)p;          p += (size_t)KS * NH * N * HD * 4;
  P.psum = (float*)p;          p += (size_t)KS * NH * N * 4;
  P.Qb   = (unsigned short*)p; p += (size_t)N * D * 2;
  P.Kb   = (unsigned short*)p; p += (size_t)N * D * 2;
  P.Vtb  = (unsigned short*)p; p += (size_t)D * N * 2;
  P.x2b_full = (unsigned short*)p; p += (size_t)NGR * D * 2;
  P.x2t_full = (unsigned short*)p; p += (size_t)D * NGR * 2;
  P.wh   = (unsigned short*)p; p += (size_t)768 * 256 * 2;
  P.wl   = (unsigned short*)p; p += (size_t)768 * 256 * 2;
  P.owh  = (unsigned short*)p; p += (size_t)256 * 256 * 2;
  P.owl  = (unsigned short*)p; p += (size_t)256 * 256 * 2;

  prep_kernel<<<288, 256, 0, stream>>>(P);
  mid_kernel<<<288, 256, 0, stream>>>(P);
  attn_kernel<<<dim3(KS, N / 128, NH), 128, 0, stream>>>(P);
  tail_kernel<<<72, 256, 0, stream>>>(P);
}

// Round 12
// 155.133 us; speedup vs baseline: 1.0700x; 1.0294x over previous
//
#include <hip/hip_runtime.h>
#include <math.h>

#define N 2304
#define D 256
#define NH 8
#define HD 32
#define KS 8            // key segments in attention
#define SEG (N / KS)    // 288
#define NCH (SEG / 32)  // 9
#define NGR 2320        // guarded key count (2304 + 8 each side)

typedef __attribute__((ext_vector_type(8))) short short8;   // 8 bf16
typedef __attribute__((ext_vector_type(4))) short bf16x4;   // 4 bf16
typedef __attribute__((ext_vector_type(4))) float floatx4;  // 4 fp32 (MFMA C/D)

static __device__ __forceinline__ unsigned short f2bf(float x) {
  union { float f; unsigned u; } v; v.f = x;
  unsigned r = (v.u + 0x7fffu + ((v.u >> 16) & 1u)) >> 16;   // RNE
  return (unsigned short)r;
}
static __device__ __forceinline__ float bf2f(unsigned short h) {
  union { unsigned u; float f; } v; v.u = (unsigned)h << 16;
  return v.f;
}
static __device__ __forceinline__ unsigned pack2bf(float lo, float hi) {
  return (unsigned)f2bf(lo) | ((unsigned)f2bf(hi) << 16);
}

struct Params {
  const float *x1, *x2, *lng, *lnb, *ipw, *ipb, *ow, *ob;
  float *out;
  float *pacc, *psum;
  unsigned short *Qb, *Kb, *Vtb;
  unsigned short *x2b_full, *x2t_full;
  unsigned short *x1h, *x1l, *wh, *wl, *owh, *owl;
};

// ====== K1: x1/W/outW hi-lo split + x2 bf16 row-major/transposed prep ========
__global__ __launch_bounds__(256) void prep_kernel(Params P)
{
  __shared__ unsigned short T[16][17];
  const int t = threadIdx.x, bid = blockIdx.x, NB = gridDim.x;
  for (int i = bid * 256 + t; i < 851968; i += NB * 256) {
    const float* src; unsigned short *dh, *dl; int off;
    if (i < 589824)      { src = P.x1;  dh = P.x1h; dl = P.x1l; off = i; }
    else if (i < 786432) { src = P.ipw; dh = P.wh;  dl = P.wl;  off = i - 589824; }
    else                 { src = P.ow;  dh = P.owh; dl = P.owl; off = i - 786432; }
    const float v = src[off];
    const unsigned short h = f2bf(v);
    dh[off] = h;
    dl[off] = f2bf(v - bf2f(h));
  }
  const int tx = t & 15, ty = t >> 4;
  for (int u = bid; u < 145 * 16; u += NB) {
    const int k0 = (u % 145) * 16, f0 = (u / 145) * 16;
    const int key = k0 + ty - 8;
    unsigned short v = 0;
    if (key >= 0 && key < N) v = f2bf(P.x2[(size_t)key * D + f0 + tx]);
    P.x2b_full[(size_t)(k0 + ty) * D + f0 + tx] = v;
    T[ty][tx] = v;
    __syncthreads();
    P.x2t_full[(size_t)(f0 + ty) * NGR + k0 + tx] = T[tx][ty];
    __syncthreads();
  }
}

// ====== K2 (512 thr): bid<144 stage1+Q-proj; 144<=bid<216 KV-GEMM ============
__global__ __launch_bounds__(512) void mid_kernel(Params P)
{
  __shared__ __align__(16) unsigned short Pb[16 * 552];   // probs, bf16
  __shared__ __align__(16) unsigned short xfh[16 * 264];  // x2f hi
  __shared__ __align__(16) unsigned short xfl[16 * 264];  // x2f lo
  __shared__ float dn[128], lr1[128], lr2[128];

  const int bid  = blockIdx.x;
  const int t    = threadIdx.x;
  const int w    = t >> 6;         // wave 0..7
  const int lane = t & 63;
  const int g    = lane >> 4;
  const int c    = lane & 15;
  const unsigned short* x2b = P.x2b_full + 8 * D;
  const unsigned short* x2t = P.x2t_full + 8;

  if (bid < 144) {
    const int r  = bid / 3;
    const int c0 = (bid % 3) * 16;
    const int qbase  = r * 48 + c0;
    const int row_lo = max(0, 8 - r);
    const int row_hi = min(16, 55 - r);
    const int nrows  = min(r + 8, 47) - max(r - 8, 0) + 1;

    short8 qf[8];
    {
      const unsigned short* qptr = x2b + (size_t)(qbase + c) * D + g * 8;
      #pragma unroll
      for (int si = 0; si < 8; ++si) qf[si] = *(const short8*)(qptr + si * 32);
    }

    // ---- scores: 8 waves split window rows; 16 K-frags batched per row ----
    float pssum[4] = {0.f, 0.f, 0.f, 0.f};
    for (int wr = row_lo + w; wr <= row_hi; wr += 8) {
      const int keybase = (r - 8 + wr) * 48 + c0 - 8;
      const unsigned short* kp0 = x2b + (size_t)(keybase + c) * D + g * 8;
      const unsigned short* kp1 = x2b + (size_t)(keybase + 16 + c) * D + g * 8;
      short8 kA[8], kB[8];
      #pragma unroll
      for (int si = 0; si < 8; ++si) {
        kA[si] = *(const short8*)(kp0 + si * 32);
        kB[si] = *(const short8*)(kp1 + si * 32);
      }
      floatx4 sa = {0.f, 0.f, 0.f, 0.f};
      floatx4 sb = {0.f, 0.f, 0.f, 0.f};
      #pragma unroll
      for (int si = 0; si < 8; ++si) {
        sa = __builtin_amdgcn_mfma_f32_16x16x32_bf16(qf[si], kA[si], sa, 0, 0, 0);
        sb = __builtin_amdgcn_mfma_f32_16x16x32_bf16(qf[si], kB[si], sb, 0, 0, 0);
      }
      #pragma unroll
      for (int ch = 0; ch < 2; ++ch) {
        const floatx4 sv4 = ch ? sb : sa;
        const int wc = ch * 16 + c;
        const int kc_img = c0 - 8 + wc;
        #pragma unroll
        for (int reg = 0; reg < 4; ++reg) {
          const int qi = g * 4 + reg;
          float sv = sv4[reg] * 0.0625f;
          const int cimg  = c0 + qi;
          const int ncols = min(cimg + 8, 47) - max(cimg - 8, 0) + 1;
          const int mult  = 289 - nrows * ncols + 1;
          const int wc0q  = (cimg >= 8) ? qi : (8 - c0);
          if (mult > 1 && wr == row_lo && wc == wc0q) sv += __logf((float)mult);
          const bool valid = (kc_img >= 0) & (kc_img < 48) &
                             (wc >= qi) & (wc <= qi + 16);
          const float pv = valid ? __expf(sv) : 0.f;
          pssum[reg] += pv;
          Pb[qi * 552 + wr * 32 + wc] = valid ? f2bf(pv) : (unsigned short)0;
        }
      }
    }
    #pragma unroll
    for (int off = 1; off <= 8; off <<= 1) {
      #pragma unroll
      for (int reg = 0; reg < 4; ++reg) pssum[reg] += __shfl_xor(pssum[reg], off);
    }
    if (c == 0) {
      #pragma unroll
      for (int reg = 0; reg < 4; ++reg) dn[w * 16 + g * 4 + reg] = pssum[reg];
    }
    __syncthreads();

    // ---- PV: wave owns 32 feats; next-iter prefetch ----
    floatx4 acc0 = {0.f, 0.f, 0.f, 0.f};
    floatx4 acc1 = {0.f, 0.f, 0.f, 0.f};
    const int fb = w * 32;
    const unsigned short* vrow0 = x2t + (size_t)(fb + c) * NGR;
    const unsigned short* vrow1 = x2t + (size_t)(fb + 16 + c) * NGR;
    {
      int wr = row_lo;
      int kb = (r - 8 + wr) * 48 + c0 - 8 + g * 8;
      short8 pA = *(const short8*)&Pb[c * 552 + wr * 32 + g * 8];
      short8 v0 = *(const short8*)(vrow0 + kb);
      short8 v1 = *(const short8*)(vrow1 + kb);
      for (; wr <= row_hi; ++wr) {
        const int wn  = (wr < row_hi) ? wr + 1 : row_lo;   // harmless reload
        const int kbn = (r - 8 + wn) * 48 + c0 - 8 + g * 8;
        short8 pAn = *(const short8*)&Pb[c * 552 + wn * 32 + g * 8];
        short8 v0n = *(const short8*)(vrow0 + kbn);
        short8 v1n = *(const short8*)(vrow1 + kbn);
        acc0 = __builtin_amdgcn_mfma_f32_16x16x32_bf16(pA, v0, acc0, 0, 0, 0);
        acc1 = __builtin_amdgcn_mfma_f32_16x16x32_bf16(pA, v1, acc1, 0, 0, 0);
        pA = pAn; v0 = v0n; v1 = v1n;
      }
    }

    // ---- epilogue: /denom, LN, hi/lo into LDS ----
    float vout[2][4], ps1[4] = {0,0,0,0}, ps2[4] = {0,0,0,0};
    #pragma unroll
    for (int reg = 0; reg < 4; ++reg) {
      const int m = g * 4 + reg;
      float den = 0.f;
      #pragma unroll
      for (int ww = 0; ww < 8; ++ww) den += dn[ww * 16 + m];
      const float di = 1.f / den;
      const float v0 = acc0[reg] * di;
      const float v1 = acc1[reg] * di;
      vout[0][reg] = v0; vout[1][reg] = v1;
      ps1[reg] += v0 + v1;
      ps2[reg] += v0 * v0 + v1 * v1;
    }
    #pragma unroll
    for (int off = 1; off <= 8; off <<= 1) {
      #pragma unroll
      for (int reg = 0; reg < 4; ++reg) {
        ps1[reg] += __shfl_xor(ps1[reg], off);
        ps2[reg] += __shfl_xor(ps2[reg], off);
      }
    }
    if (c == 0) {
      #pragma unroll
      for (int reg = 0; reg < 4; ++reg) {
        lr1[w * 16 + g * 4 + reg] = ps1[reg];
        lr2[w * 16 + g * 4 + reg] = ps2[reg];
      }
    }
    __syncthreads();
    #pragma unroll
    for (int reg = 0; reg < 4; ++reg) {
      const int m = g * 4 + reg;
      float s1 = 0.f, s2 = 0.f;
      #pragma unroll
      for (int ww = 0; ww < 8; ++ww) { s1 += lr1[ww * 16 + m]; s2 += lr2[ww * 16 + m]; }
      const float mu  = s1 * (1.f / 256.f);
      const float var = s2 * (1.f / 256.f) - mu * mu;
      const float rs  = rsqrtf(var + 1e-5f);
      #pragma unroll
      for (int ng = 0; ng < 2; ++ng) {
        const int f = fb + ng * 16 + c;
        const float val = (vout[ng][reg] - mu) * rs * P.lng[f] + P.lnb[f];
        const unsigned short h = f2bf(val);
        xfh[m * 264 + f] = h;
        xfl[m * 264 + f] = f2bf(val - bf2f(h));
      }
    }
    __syncthreads();

    // ---- fused Q-proj: wave owns 32 cols; next-kc prefetch ----
    const int nw = w * 32;
    const unsigned short* bh0p = P.wh + (size_t)(nw + c) * 256 + g * 8;
    const unsigned short* bh1p = P.wh + (size_t)(nw + 16 + c) * 256 + g * 8;
    const unsigned short* bl0p = P.wl + (size_t)(nw + c) * 256 + g * 8;
    const unsigned short* bl1p = P.wl + (size_t)(nw + 16 + c) * 256 + g * 8;
    floatx4 q0 = {0.f, 0.f, 0.f, 0.f};
    floatx4 q1 = {0.f, 0.f, 0.f, 0.f};
    short8 bh0 = *(const short8*)bh0p;
    short8 bh1 = *(const short8*)bh1p;
    short8 bl0 = *(const short8*)bl0p;
    short8 bl1 = *(const short8*)bl1p;
    for (int kc = 0; kc < 256; kc += 32) {
      const int kn = (kc + 32 < 256) ? kc + 32 : 0;
      short8 nbh0 = *(const short8*)(bh0p + kn);
      short8 nbh1 = *(const short8*)(bh1p + kn);
      short8 nbl0 = *(const short8*)(bl0p + kn);
      short8 nbl1 = *(const short8*)(bl1p + kn);
      const short8 ah = *(const short8*)&xfh[c * 264 + kc + g * 8];
      const short8 al = *(const short8*)&xfl[c * 264 + kc + g * 8];
      q0 = __builtin_amdgcn_mfma_f32_16x16x32_bf16(ah, bh0, q0, 0, 0, 0);
      q0 = __builtin_amdgcn_mfma_f32_16x16x32_bf16(al, bh0, q0, 0, 0, 0);
      q0 = __builtin_amdgcn_mfma_f32_16x16x32_bf16(ah, bl0, q0, 0, 0, 0);
      q1 = __builtin_amdgcn_mfma_f32_16x16x32_bf16(ah, bh1, q1, 0, 0, 0);
      q1 = __builtin_amdgcn_mfma_f32_16x16x32_bf16(al, bh1, q1, 0, 0, 0);
      q1 = __builtin_amdgcn_mfma_f32_16x16x32_bf16(ah, bl1, q1, 0, 0, 0);
      bh0 = nbh0; bh1 = nbh1; bl0 = nbl0; bl1 = nbl1;
    }
    const float qscale = 0.17677669529663687f;   // 1/sqrt(32)
    #pragma unroll
    for (int nt = 0; nt < 2; ++nt) {
      const int j = nw + nt * 16 + c;
      const float bj = P.ipb[j];
      const floatx4 qa = nt ? q1 : q0;
      #pragma unroll
      for (int reg = 0; reg < 4; ++reg) {
        const int m = qbase + 4 * g + reg;
        P.Qb[(size_t)m * 256 + j] = f2bf((qa[reg] + bj) * qscale);
      }
    }
  } else if (bid < 216) {
    // ---- KV-GEMM: pre-split x1h/x1l, 3-pass, next-kc prefetch ----
    const int idx = bid - 144;
    const int m0  = (idx >> 1) * 64;
    const int nw  = 256 + (idx & 1) * 256 + w * 32;
    floatx4 acc[4][2];
    #pragma unroll
    for (int mt = 0; mt < 4; ++mt)
      #pragma unroll
      for (int nt = 0; nt < 2; ++nt) acc[mt][nt] = (floatx4){0.f, 0.f, 0.f, 0.f};

    const unsigned short* ahp[4];
    const unsigned short* alp[4];
    #pragma unroll
    for (int mt = 0; mt < 4; ++mt) {
      ahp[mt] = P.x1h + (size_t)(m0 + mt * 16 + c) * 256 + g * 8;
      alp[mt] = P.x1l + (size_t)(m0 + mt * 16 + c) * 256 + g * 8;
    }
    const unsigned short* bhp[2];
    const unsigned short* blp[2];
    #pragma unroll
    for (int nt = 0; nt < 2; ++nt) {
      bhp[nt] = P.wh + (size_t)(nw + nt * 16 + c) * 256 + g * 8;
      blp[nt] = P.wl + (size_t)(nw + nt * 16 + c) * 256 + g * 8;
    }
    short8 ah[4], al[4], bh[2], bl[2];
    #pragma unroll
    for (int mt = 0; mt < 4; ++mt) { ah[mt] = *(const short8*)ahp[mt]; al[mt] = *(const short8*)alp[mt]; }
    #pragma unroll
    for (int nt = 0; nt < 2; ++nt) { bh[nt] = *(const short8*)bhp[nt]; bl[nt] = *(const short8*)blp[nt]; }

    for (int kc = 0; kc < 256; kc += 32) {
      const int kn = (kc + 32 < 256) ? kc + 32 : 0;
      short8 nah[4], nal[4], nbh[2], nbl[2];
      #pragma unroll
      for (int mt = 0; mt < 4; ++mt) {
        nah[mt] = *(const short8*)(ahp[mt] + kn);
        nal[mt] = *(const short8*)(alp[mt] + kn);
      }
      #pragma unroll
      for (int nt = 0; nt < 2; ++nt) {
        nbh[nt] = *(const short8*)(bhp[nt] + kn);
        nbl[nt] = *(const short8*)(blp[nt] + kn);
      }
      #pragma unroll
      for (int mt = 0; mt < 4; ++mt)
        #pragma unroll
        for (int nt = 0; nt < 2; ++nt) {
          acc[mt][nt] = __builtin_amdgcn_mfma_f32_16x16x32_bf16(ah[mt], bh[nt], acc[mt][nt], 0, 0, 0);
          acc[mt][nt] = __builtin_amdgcn_mfma_f32_16x16x32_bf16(al[mt], bh[nt], acc[mt][nt], 0, 0, 0);
          acc[mt][nt] = __builtin_amdgcn_mfma_f32_16x16x32_bf16(ah[mt], bl[nt], acc[mt][nt], 0, 0, 0);
        }
      #pragma unroll
      for (int mt = 0; mt < 4; ++mt) { ah[mt] = nah[mt]; al[mt] = nal[mt]; }
      #pragma unroll
      for (int nt = 0; nt < 2; ++nt) { bh[nt] = nbh[nt]; bl[nt] = nbl[nt]; }
    }
    #pragma unroll
    for (int mt = 0; mt < 4; ++mt)
      #pragma unroll
      for (int nt = 0; nt < 2; ++nt) {
        const int j = nw + nt * 16 + c;
        const float bj = P.ipb[j];
        #pragma unroll
        for (int rr = 0; rr < 4; ++rr) {
          const int m = m0 + mt * 16 + 4 * g + rr;
          const float v = acc[mt][nt][rr] + bj;
          if (j < 512) P.Kb[(size_t)m * 256 + (j - 256)] = f2bf(v);
          else         P.Vtb[(size_t)(j - 512) * N + m] = f2bf(v);
        }
      }
  }
}

// ============ K3: MFMA flash attention (KS=8, 128 thr, LDS dbuf) =============
__global__ __launch_bounds__(128) void attn_kernel(Params P)
{
  __shared__ __align__(16) unsigned short Ksh[2][32 * 40];
  __shared__ __align__(16) unsigned short Vsh[2][32 * 40];

  const int t    = threadIdx.x;
  const int wv   = t >> 6;
  const int lane = t & 63;
  const int g    = lane >> 4;
  const int c    = lane & 15;
  const int seg  = blockIdx.x;
  const int qb   = blockIdx.y;
  const int head = blockIdx.z;
  const int q0w  = qb * 128 + wv * 64;
  const int key0 = seg * SEG;

  short8 qf[4];
  #pragma unroll
  for (int qt = 0; qt < 4; ++qt)
    qf[qt] = *(const short8*)(P.Qb + (size_t)(q0w + qt * 16 + c) * D + head * HD + g * 8);

  const unsigned short* ksrc = P.Kb  + (size_t)(key0 + t / 4) * D + head * HD + (t % 4) * 8;
  const unsigned short* vsrc = P.Vtb + (size_t)(head * HD + t / 4) * N + key0 + (t % 4) * 8;
  const int sdst = (t / 4) * 40 + (t % 4) * 8;

  {
    const float4 gk = *(const float4*)ksrc;
    const float4 gv = *(const float4*)vsrc;
    *(float4*)&Ksh[0][sdst] = gk;
    *(float4*)&Vsh[0][sdst] = gv;
  }
  __syncthreads();

  floatx4 accL[4], accH[4];
  float ssum[4];
  #pragma unroll
  for (int qt = 0; qt < 4; ++qt) {
    accL[qt] = (floatx4){0.f, 0.f, 0.f, 0.f};
    accH[qt] = (floatx4){0.f, 0.f, 0.f, 0.f};
    ssum[qt] = 0.f;
  }

  for (int ch = 0; ch < NCH; ++ch) {
    float4 gk, gv;
    const bool more = (ch + 1 < NCH);
    if (more) {
      gk = *(const float4*)(ksrc + (size_t)(ch + 1) * 32 * D);
      gv = *(const float4*)(vsrc + (ch + 1) * 32);
    }
    const unsigned short* kb = Ksh[ch & 1];
    const unsigned short* vb = Vsh[ch & 1];

    #pragma unroll
    for (int kk = 0; kk < 2; ++kk) {
      const short8 kf  = *(const short8*)&kb[(kk * 16 + c) * 40 + g * 8];
      const bf16x4 vf0 = *(const bf16x4*)&vb[c * 40 + kk * 16 + g * 4];
      const bf16x4 vf1 = *(const bf16x4*)&vb[(16 + c) * 40 + kk * 16 + g * 4];
      #pragma unroll
      for (int qt = 0; qt < 4; ++qt) {
        const floatx4 z = {0.f, 0.f, 0.f, 0.f};
        floatx4 sA = __builtin_amdgcn_mfma_f32_16x16x32_bf16(kf, qf[qt], z, 0, 0, 0);
        const float p0 = __expf(sA[0]);
        const float p1 = __expf(sA[1]);
        const float p2 = __expf(sA[2]);
        const float p3 = __expf(sA[3]);
        ssum[qt] += (p0 + p1) + (p2 + p3);
        union { unsigned u[2]; bf16x4 s; } pB;
        pB.u[0] = pack2bf(p0, p1);
        pB.u[1] = pack2bf(p2, p3);
        accL[qt] = __builtin_amdgcn_mfma_f32_16x16x16bf16_1k(vf0, pB.s, accL[qt], 0, 0, 0);
        accH[qt] = __builtin_amdgcn_mfma_f32_16x16x16bf16_1k(vf1, pB.s, accH[qt], 0, 0, 0);
      }
    }
    if (more) {
      *(float4*)&Ksh[(ch + 1) & 1][sdst] = gk;
      *(float4*)&Vsh[(ch + 1) & 1][sdst] = gv;
    }
    __syncthreads();
  }

  #pragma unroll
  for (int qt = 0; qt < 4; ++qt) {
    float s = ssum[qt];
    s += __shfl_xor(s, 16);
    s += __shfl_xor(s, 32);
    const size_t row = (size_t)(seg * NH + head) * N + q0w + qt * 16 + c;
    *(float4*)(P.pacc + row * HD + g * 4) =
        make_float4(accL[qt][0], accL[qt][1], accL[qt][2], accL[qt][3]);
    *(float4*)(P.pacc + row * HD + 16 + g * 4) =
        make_float4(accH[qt][0], accH[qt][1], accH[qt][2], accH[qt][3]);
    if (g == 0) P.psum[row] = s;
  }
}

// ============ K4: combine + out-projection (fused, 72 blocks) ================
__global__ __launch_bounds__(256) void tail_kernel(Params P)
{
  __shared__ __align__(16) unsigned short oht[32 * 264];
  __shared__ __align__(16) unsigned short olt[32 * 264];
  const int bid  = blockIdx.x;
  const int t    = threadIdx.x;
  const int wv   = t >> 6;
  const int lane = t & 63;
  const int g    = lane >> 4;
  const int c    = lane & 15;
  const int m0 = bid * 32;
  {
    const int row = t >> 3;
    const int hh  = t & 7;
    const int mrow = m0 + row;
    float den = 0.f;
    #pragma unroll
    for (int sgi = 0; sgi < KS; ++sgi)
      den += P.psum[(size_t)(sgi * NH + hh) * N + mrow];
    const float dinv = 1.f / den;
    #pragma unroll
    for (int c4 = 0; c4 < 8; ++c4) {
      float ax = 0.f, ay = 0.f, az = 0.f, aw = 0.f;
      #pragma unroll
      for (int sgi = 0; sgi < KS; ++sgi) {
        const float4 pv = *(const float4*)&P.pacc[((size_t)(sgi * NH + hh) * N + mrow) * HD + c4 * 4];
        ax += pv.x; ay += pv.y; az += pv.z; aw += pv.w;
      }
      const int f0 = hh * 32 + c4 * 4;
      const float vv[4] = {ax * dinv, ay * dinv, az * dinv, aw * dinv};
      #pragma unroll
      for (int e = 0; e < 4; ++e) {
        const unsigned short h = f2bf(vv[e]);
        oht[row * 264 + f0 + e] = h;
        olt[row * 264 + f0 + e] = f2bf(vv[e] - bf2f(h));
      }
    }
  }
  __syncthreads();

  const int nw = wv * 64;
  floatx4 acc[2][4];
  #pragma unroll
  for (int mt = 0; mt < 2; ++mt)
    #pragma unroll
    for (int nt = 0; nt < 4; ++nt) acc[mt][nt] = (floatx4){0.f, 0.f, 0.f, 0.f};
  #pragma unroll
  for (int pass = 0; pass < 3; ++pass) {
    const unsigned short* Ap = (pass == 1) ? olt : oht;
    const unsigned short* Wp = (pass == 2) ? P.owl : P.owh;
    #pragma unroll
    for (int kc = 0; kc < 256; kc += 32) {
      short8 af[2], bf[4];
      #pragma unroll
      for (int mt = 0; mt < 2; ++mt)
        af[mt] = *(const short8*)&Ap[(mt * 16 + c) * 264 + kc + g * 8];
      #pragma unroll
      for (int nt = 0; nt < 4; ++nt)
        bf[nt] = *(const short8*)(Wp + (size_t)(nw + nt * 16 + c) * 256 + kc + g * 8);
      #pragma unroll
      for (int mt = 0; mt < 2; ++mt)
        #pragma unroll
        for (int nt = 0; nt < 4; ++nt)
          acc[mt][nt] = __builtin_amdgcn_mfma_f32_16x16x32_bf16(af[mt], bf[nt], acc[mt][nt], 0, 0, 0);
    }
  }
  #pragma unroll
  for (int mt = 0; mt < 2; ++mt)
    #pragma unroll
    for (int nt = 0; nt < 4; ++nt) {
      const int j = nw + nt * 16 + c;
      const float bj = P.ob[j];
      #pragma unroll
      for (int rr = 0; rr < 4; ++rr) {
        const int m = m0 + mt * 16 + 4 * g + rr;
        P.out[(size_t)m * 256 + j] = acc[mt][nt][rr] + bj;
      }
    }
}

extern "C" void kernel_launch(void* const* d_in, const int* in_sizes, int n_in,
                              void* d_out, int out_size, void* d_ws, size_t ws_size,
                              hipStream_t stream)
{
  (void)in_sizes; (void)n_in; (void)out_size; (void)ws_size;
  Params P;
  P.x1  = (const float*)d_in[0];
  P.x2  = (const float*)d_in[1];
  P.lng = (const float*)d_in[2];
  P.lnb = (const float*)d_in[3];
  P.ipw = (const float*)d_in[4];
  P.ipb = (const float*)d_in[5];
  P.ow  = (const float*)d_in[6];
  P.ob  = (const float*)d_in[7];
  P.out = (float*)d_out;

  char* p = (char*)d_ws;
  P.pacc = (float*)p;          p += (size_t)KS * NH * N * HD * 4;
  P.psum = (float*)p;          p += (size_t)KS * NH * N * 4;
  P.Qb   = (unsigned short*)p; p += (size_t)N * D * 2;
  P.Kb   = (unsigned short*)p; p += (size_t)N * D * 2;
  P.Vtb  = (unsigned short*)p; p += (size_t)D * N * 2;
  P.x2b_full = (unsigned short*)p; p += (size_t)NGR * D * 2;
  P.x2t_full = (unsigned short*)p; p += (size_t)D * NGR * 2;
  P.x1h  = (unsigned short*)p; p += (size_t)N * D * 2;
  P.x1l  = (unsigned short*)p; p += (size_t)N * D * 2;
  P.wh   = (unsigned short*)p; p += (size_t)768 * 256 * 2;
  P.wl   = (unsigned short*)p; p += (size_t)768 * 256 * 2;
  P.owh  = (unsigned short*)p; p += (size_t)256 * 256 * 2;
  P.owl  = (unsigned short*)p; p += (size_t)256 * 256 * 2;

  prep_kernel<<<288, 256, 0, stream>>>(P);
  mid_kernel<<<216, 512, 0, stream>>>(P);
  attn_kernel<<<dim3(KS, N / 128, NH), 128, 0, stream>>>(P);
  tail_kernel<<<72, 256, 0, stream>>>(P);
}